// Round 5
// baseline (127.091 us; speedup 1.0000x reference)
//
#include <hip/hip_runtime.h>

// Problem constants (fixed by reference)
#define BATCH   16384
#define NFEAT   512
#define NTREE   64
#define NDEPTH  6
#define NLEAF   64
#define NDOUT   64
#define NLOGIT  384   // NDEPTH * NTREE

typedef float    f32x4  __attribute__((ext_vector_type(4)));
typedef _Float16 half8  __attribute__((ext_vector_type(8)));
typedef __fp16   fp16x2 __attribute__((ext_vector_type(2)));

union H8 { _Float16 h[8]; half8 v; uint4 q; };
union H4 { _Float16 h[4]; ushort4 u; };

// async global->LDS DMA, 16B per lane; lds dest wave-uniform base,
// HW writes lane i at base + i*16 (m97/m104 semantics).
__device__ __forceinline__ void dma16(const void* g, void* l) {
    __builtin_amdgcn_global_load_lds(
        (const __attribute__((address_space(1))) unsigned int*)g,
        (__attribute__((address_space(3))) unsigned int*)l, 16, 0, 0);
}

// ---------------------------------------------------------------------------
// prep: blocks 0..63   -> V2[t][d][l] = f16(leaf[t][l][d] / 64)
//       blocks 64..159 -> Wt[n][f-blocks, groups-of-8 XOR-swizzled by n&7]
//                         = f16(W[d][f][t]),  n = d*64+t
// ---------------------------------------------------------------------------
__global__ __launch_bounds__(256) void prep(const float* __restrict__ leaf,
                                            const float* __restrict__ W,
                                            _Float16* __restrict__ V2,
                                            _Float16* __restrict__ Wt) {
    __shared__ float T[64 * 65];
    const int tid = threadIdx.x;
    if (blockIdx.x < 64) {
        const int t = blockIdx.x;
        const float* src = leaf + (size_t)t * 4096;
        for (int j = 0; j < 4; ++j) {
            int idx = tid + 256 * j;            // 0..1023 float4s
            int l = idx >> 4, d4 = idx & 15;
            float4 v = *(const float4*)(src + l * 64 + d4 * 4);
            T[l * 65 + d4 * 4 + 0] = v.x;
            T[l * 65 + d4 * 4 + 1] = v.y;
            T[l * 65 + d4 * 4 + 2] = v.z;
            T[l * 65 + d4 * 4 + 3] = v.w;
        }
        __syncthreads();
        _Float16* dst = V2 + (size_t)t * 4096;
        for (int j = 0; j < 4; ++j) {
            int idx = tid + 256 * j;
            int d = idx >> 4, l4 = idx & 15;
            H4 u;
            u.h[0] = (_Float16)(T[(l4 * 4 + 0) * 65 + d] * 0.015625f);
            u.h[1] = (_Float16)(T[(l4 * 4 + 1) * 65 + d] * 0.015625f);
            u.h[2] = (_Float16)(T[(l4 * 4 + 2) * 65 + d] * 0.015625f);
            u.h[3] = (_Float16)(T[(l4 * 4 + 3) * 65 + d] * 0.015625f);
            *(ushort4*)(dst + d * 64 + l4 * 4) = u.u;
        }
    } else {
        const int bid = blockIdx.x - 64;        // 0..95
        const int d = bid >> 4, f0 = (bid & 15) * 32;
        for (int j = 0; j < 2; ++j) {
            int idx = tid + 256 * j;            // 0..511 float4s (32 f x 64 t)
            int f = idx >> 4, c4 = idx & 15;
            float4 v = *(const float4*)(W + ((size_t)d * 512 + f0 + f) * 64 + c4 * 4);
            T[f * 65 + c4 * 4 + 0] = v.x;
            T[f * 65 + c4 * 4 + 1] = v.y;
            T[f * 65 + c4 * 4 + 2] = v.z;
            T[f * 65 + c4 * 4 + 3] = v.w;
        }
        __syncthreads();
        const int t = tid >> 2, c8 = tid & 3;
        H8 u;
        #pragma unroll
        for (int i = 0; i < 8; ++i) u.h[i] = (_Float16)T[(c8 * 8 + i) * 65 + t];
        int g  = ((f0 & 63) >> 3) + c8;         // k-group 0..7 in this 64-block
        int gs = g ^ (t & 7);                   // (n&7) == (t&7)
        *(half8*)(Wt + ((size_t)(d * 64 + t)) * 512 + (f0 & ~63) + gs * 8) = u.v;
    }
}

// ---------------------------------------------------------------------------
// gemm1: SPT[n][b] = f16(sigmoid(sum_f x[b][f]*W[f][n] + bias[n])), n=d*64+t
// BM=64 rows x BN=192 n (3 levels) per block, BK=64; grid (256,2)=512 = 2/CU.
// A: manual stage fp32->f16 (cvt_pkrtz) with XOR-swizzled groups -> conversion
//    paid ONCE per element; x streamed only 2x (67 MB).
// B: global_load_lds from pre-swizzled f16 Wt (L2-resident).
// Wave tile 64x48: mt4 x nt3 x ks2 = 24 MFMA/iter.
// ---------------------------------------------------------------------------
__global__ __launch_bounds__(256) void gemm1(const float* __restrict__ x,
                                             const _Float16* __restrict__ Wt,
                                             const float* __restrict__ bias,
                                             _Float16* __restrict__ SPT) {
    __shared__ _Float16 SM[16384];            // 32 KB
    _Float16* As = SM;                        // [64 r][64 k swizzled]  8 KB
    _Float16* Bs = SM + 4096;                 // [192 n][64 k swizzled] 24 KB
    const int tid  = threadIdx.x;
    const int wave = tid >> 6, lane = tid & 63;
    const int quad = lane >> 4, l15 = lane & 15;
    const int bm = blockIdx.x, bn = blockIdx.y;

    const int s_row = tid >> 3, s_c8 = tid & 7;   // A-stage mapping
    const int b_r8  = lane >> 3, b_c8 = lane & 7; // B-DMA lane mapping

    f32x4 acc[4][3];
    #pragma unroll
    for (int mt = 0; mt < 4; ++mt)
        #pragma unroll
        for (int nt = 0; nt < 3; ++nt)
            acc[mt][nt] = (f32x4){0.f, 0.f, 0.f, 0.f};

    for (int k0 = 0; k0 < NFEAT; k0 += 64) {
        // ---- B stage: 6 DMA insts/wave, 1 KB each (8 rows x 128 B), linear
        #pragma unroll
        for (int i = 0; i < 6; ++i) {
            int nl = wave * 48 + i * 8;
            const _Float16* g = Wt + (size_t)(bn * 192 + nl + b_r8) * 512 + k0 + b_c8 * 8;
            dma16(g, (char*)Bs + (size_t)nl * 128);
        }
        // ---- A stage: manual fp32->f16, swizzled group write (2 groups/thread)
        #pragma unroll
        for (int i = 0; i < 2; ++i) {
            int row = s_row + i * 32;             // 0..63
            const float* src = x + (size_t)(bm * 64 + row) * NFEAT + k0 + s_c8 * 8;
            float4 v0 = *(const float4*)(src);
            float4 v1 = *(const float4*)(src + 4);
            H8 u;
            *(fp16x2*)&u.h[0] = __builtin_amdgcn_cvt_pkrtz(v0.x, v0.y);
            *(fp16x2*)&u.h[2] = __builtin_amdgcn_cvt_pkrtz(v0.z, v0.w);
            *(fp16x2*)&u.h[4] = __builtin_amdgcn_cvt_pkrtz(v1.x, v1.y);
            *(fp16x2*)&u.h[6] = __builtin_amdgcn_cvt_pkrtz(v1.z, v1.w);
            *(half8*)(As + row * 64 + ((s_c8 ^ (row & 7)) * 8)) = u.v;
        }
        __syncthreads();

        half8 bF[3][2];
        #pragma unroll
        for (int nt = 0; nt < 3; ++nt) {
            int n = wave * 48 + nt * 16 + l15;
            #pragma unroll
            for (int ks = 0; ks < 2; ++ks) {
                int g = (ks * 4 + quad) ^ (n & 7);
                bF[nt][ks] = *(const half8*)(Bs + n * 64 + g * 8);
            }
        }
        half8 aF[4][2];
        #pragma unroll
        for (int mt = 0; mt < 4; ++mt) {
            int r = mt * 16 + l15;
            #pragma unroll
            for (int ks = 0; ks < 2; ++ks) {
                int g = (ks * 4 + quad) ^ (r & 7);
                aF[mt][ks] = *(const half8*)(As + r * 64 + g * 8);
            }
        }
        #pragma unroll
        for (int mt = 0; mt < 4; ++mt)
            #pragma unroll
            for (int nt = 0; nt < 3; ++nt)
                #pragma unroll
                for (int ks = 0; ks < 2; ++ks)
                    acc[mt][nt] = __builtin_amdgcn_mfma_f32_16x16x32_f16(
                        aF[mt][ks], bF[nt][ks], acc[mt][nt], 0, 0, 0);
        __syncthreads();
    }

    // ---- epilogue: bias + sigmoid -> f16; transpose via LDS (reuse SM);
    //      C/D layout: col(n)=l15, row(m)=quad*4+reg.
    _Float16* Tr = SM;                        // [192 n][72 b-pad] 27.6 KB
    #pragma unroll
    for (int nt = 0; nt < 3; ++nt) {
        int nl = wave * 48 + nt * 16 + l15;
        float bv = bias[bn * 192 + nl];
        #pragma unroll
        for (int mt = 0; mt < 4; ++mt) {
            int bl = mt * 16 + quad * 4;
            H4 h;
            #pragma unroll
            for (int r = 0; r < 4; ++r) {
                float z = acc[mt][nt][r] + bv;
                h.h[r] = (_Float16)(1.0f / (1.0f + __expf(-z)));
            }
            *(ushort4*)(Tr + nl * 72 + bl) = h.u;
        }
    }
    __syncthreads();
    #pragma unroll
    for (int j = 0; j < 6; ++j) {
        int c = tid + 256 * j;                // 0..1535: 192 n x 8 chunks
        int nl = c >> 3, off = c & 7;
        uint4 v = *(const uint4*)(Tr + nl * 72 + off * 8);
        *(uint4*)((unsigned short*)SPT + (size_t)(bn * 192 + nl) * BATCH
                  + bm * 64 + off * 8) = v;
    }
}

// ---------------------------------------------------------------------------
// tree_all: out[b][d] = sum_t sum_l P[b,t,l] * V2[t][d][l]
// Grid 512 (32-row tiles), wave w owns trees [16w,16w+16). Split-probs are
// transposed ONCE in LDS to sp2[t][row][8] so the P-build needs a single
// ds_read_b128 per mt; all P math in scalar f16 feeding f16 MFMA directly
// (zero conversions). bF double-buffered from L2-hot V2.
// ---------------------------------------------------------------------------
__global__ __launch_bounds__(256) void tree_all(const _Float16* __restrict__ SPT,
                                                const _Float16* __restrict__ V2,
                                                float* __restrict__ out) {
    __shared__ _Float16 spA[NLOGIT * 32];     // [n][b_loc]            24 KB
    __shared__ _Float16 sp2[64 * 32 * 8];     // [t][b_loc][p0..p5,_,_] 32 KB
    __shared__ _Float16 red[4 * 64 * 40];     // [wave][d][b_loc+pad]  20 KB
    const int tid  = threadIdx.x;
    const int w = tid >> 6, lane = tid & 63;
    const int quad = lane >> 4, l15 = lane & 15;
    const int r0 = blockIdx.x * 32;

    // stage split-probs: 384 n x 32 b f16, 16 B chunks, coalesced
    #pragma unroll
    for (int j = 0; j < 6; ++j) {
        int c = tid + 256 * j;                // 0..1535
        int n = c >> 2, c8 = c & 3;
        *(uint4*)(spA + n * 32 + c8 * 8) =
            *(const uint4*)(SPT + (size_t)n * BATCH + r0 + c8 * 8);
    }
    __syncthreads();
    // transpose to per-(t,b) packed p-vectors
    #pragma unroll
    for (int i = 0; i < 8; ++i) {
        int e = tid + 256 * i;                // 0..2047
        int t = e >> 5, bl = e & 31;
        H8 pk;
        #pragma unroll
        for (int d = 0; d < 6; ++d) pk.h[d] = spA[(d * 64 + t) * 32 + bl];
        pk.h[6] = (_Float16)0.f; pk.h[7] = (_Float16)0.f;
        *(uint4*)(sp2 + ((size_t)t * 32 + bl) * 8) = pk.q;
    }
    __syncthreads();

    f32x4 acc[2][4];
    #pragma unroll
    for (int mt = 0; mt < 2; ++mt)
        #pragma unroll
        for (int nt = 0; nt < 4; ++nt)
            acc[mt][nt] = (f32x4){0.f, 0.f, 0.f, 0.f};

    auto loadB = [&](int t, half8 (*bf)[2]) {
        #pragma unroll
        for (int nt = 0; nt < 4; ++nt)
            #pragma unroll
            for (int ks = 0; ks < 2; ++ks)
                bf[nt][ks] = *(const half8*)(V2 + (size_t)t * 4096 +
                                             (nt * 16 + l15) * 64 + ks * 32 + quad * 8);
    };
    const _Float16 one = (_Float16)1.0f;
    auto buildA = [&](int t, half8 (*af)[2]) {
        #pragma unroll
        for (int mt = 0; mt < 2; ++mt) {
            half8 pv = *(const half8*)(sp2 + ((size_t)t * 32 + mt * 16 + l15) * 8);
            _Float16 p0 = pv[0], p1 = pv[1], p2 = pv[2];
            _Float16 p3 = pv[3], p4 = pv[4], p5 = pv[5];
            _Float16 q1 = (quad & 2) ? (_Float16)(one - p1) : p1;
            _Float16 q2 = (quad & 1) ? (_Float16)(one - p2) : p2;
            _Float16 pre  = q1 * q2;
            _Float16 pre0 = p0 * pre;
            _Float16 pre1 = (one - p0) * pre;
            _Float16 t5a = p5, t5b = one - p5;
            _Float16 t34[4];
            t34[0] = p3 * p4;
            t34[1] = p3 * (one - p4);
            t34[2] = (one - p3) * p4;
            t34[3] = (one - p3) * (one - p4);
            H8 a0, a1;
            #pragma unroll
            for (int j = 0; j < 8; ++j) {
                _Float16 wj = t34[j >> 1] * ((j & 1) ? t5b : t5a);
                a0.h[j] = pre0 * wj;
                a1.h[j] = pre1 * wj;
            }
            af[mt][0] = a0.v;
            af[mt][1] = a1.v;
        }
    };

    half8 bA[4][2], bB[4][2], aF[2][2];
    loadB(w * 16, bA);
    #pragma unroll 2
    for (int tl = 0; tl < 16; ++tl) {
        const int t = w * 16 + tl;
        half8 (*cur)[2] = (tl & 1) ? bB : bA;
        half8 (*nxt)[2] = (tl & 1) ? bA : bB;
        if (tl + 1 < 16) loadB(t + 1, nxt);   // in flight over the aF build
        buildA(t, aF);
        #pragma unroll
        for (int mt = 0; mt < 2; ++mt)
            #pragma unroll
            for (int nt = 0; nt < 4; ++nt)
                #pragma unroll
                for (int ks = 0; ks < 2; ++ks)
                    acc[mt][nt] = __builtin_amdgcn_mfma_f32_16x16x32_f16(
                        aF[mt][ks], cur[nt][ks], acc[mt][nt], 0, 0, 0);
    }

    // cross-wave reduce: f16 partials [w][d][b]
    #pragma unroll
    for (int mt = 0; mt < 2; ++mt)
        #pragma unroll
        for (int nt = 0; nt < 4; ++nt) {
            H4 h;
            #pragma unroll
            for (int r = 0; r < 4; ++r) h.h[r] = (_Float16)acc[mt][nt][r];
            *(ushort4*)(red + (w * 64 + nt * 16 + l15) * 40 + mt * 16 + quad * 4) = h.u;
        }
    __syncthreads();
    {
        int b = tid >> 3;                     // 0..31
        int doff = (tid & 7) * 8;             // 0..56
        float s[8];
        #pragma unroll
        for (int i = 0; i < 8; ++i) s[i] = 0.f;
        #pragma unroll
        for (int ww = 0; ww < 4; ++ww)
            #pragma unroll
            for (int i = 0; i < 8; ++i)
                s[i] += (float)red[(ww * 64 + doff + i) * 40 + b];
        float4 o0 = { s[0], s[1], s[2], s[3] };
        float4 o1 = { s[4], s[5], s[6], s[7] };
        float* dst = out + (size_t)(r0 + b) * NDOUT + doff;
        *(float4*)dst = o0;
        *(float4*)(dst + 4) = o1;
    }
}

// ---------------------------------------------------------------------------
extern "C" void kernel_launch(void* const* d_in, const int* in_sizes, int n_in,
                              void* d_out, int out_size, void* d_ws, size_t ws_size,
                              hipStream_t stream) {
    const float* x    = (const float*)d_in[0];  // (16384, 512)
    const float* W    = (const float*)d_in[1];  // (6, 512, 64)
    const float* bias = (const float*)d_in[2];  // (6, 64) flat = 384
    const float* leaf = (const float*)d_in[3];  // (64, 64, 64)
    float* out = (float*)d_out;                 // (16384, 64)

    // ws: SPT f16 [384][16384] (12.58 MB) | V2 f16 (512 KB) | Wt f16 (384 KB)
    _Float16* SPT = (_Float16*)d_ws;
    _Float16* V2  = (_Float16*)((char*)d_ws + (size_t)NLOGIT * BATCH * 2);
    _Float16* Wt  = V2 + (size_t)NTREE * NLEAF * NDOUT;

    prep<<<160, 256, 0, stream>>>(leaf, W, V2, Wt);
    gemm1<<<dim3(BATCH / 64, 2), 256, 0, stream>>>(x, Wt, bias, SPT);
    tree_all<<<BATCH / 32, 256, 0, stream>>>(SPT, V2, out);
}